// Round 1
// baseline (152.190 us; speedup 1.0000x reference)
//
#include <hip/hip_runtime.h>

// HQQ 4-bit dequant + linear (Llama-7B up-proj, decode: 8 tokens)
// OUT=11008, IN=4096, GS=64, G=704512, OC=172 (=G/IN; OUT=64*OC)
// W_q: [32, G] int32 (one byte per word: hi nibble -> unpacked row rq,
//      lo nibble -> row rq+32 of the [64, G] tensor)
// Mapping: W_r[o, i] with r=o/172, oc=o%172, g=oc*4096+i.
//
// R4 theory: R3 gemv was in-flight-bound (~2.8 TB/s, 8 waves/CU, lumpy
// 16KB-per-wave prefetch bursts). Changes:
//  - No staging LDS: x (L2-resident, 128 KB) and scale/zero (per-XCD L2 via
//    grid swizzle) read directly -> no pre-loop barrier, LDS only 32 KB tail
//    scratch -> 4 blocks/CU (16 waves/CU) with __launch_bounds__(256,4).
//  - KS=4: per-wave Wq prefetch 8x int4 (32 VGPR), 2752 blocks, finer stagger.
//  - 1-D grid, bid = bx*688 + (oc*4+ks): 688%8==0 so the 4 bx-siblings that
//    share scale/zero/x land on the SAME XCD -> s/z stays in that XCD's L2.
//  - Tail: XOR-swizzled LDS transpose reduce (conflict-free writes, b128
//    reads, 128 parallel stores) instead of 192 shuffles + lane0-serial IO.

#define OUT_ 11008
#define IN_ 4096
#define G_ 704512
#define OC_ 172
#define KS 4
#define KC (IN_ / KS)      // 1024
#define ITERS (KC / 256)   // 4
#define SIB (OC_ * KS)     // 688 blocks sharing a bx-sibling group; 688%8==0
#define NB (4 * SIB)       // 2752 blocks

__global__ __launch_bounds__(256, 4)
void hqq_gemv(const int* __restrict__ Wq, const float* __restrict__ scale,
              const float* __restrict__ zero, const float* __restrict__ x,
              float* __restrict__ ws) {
    __shared__ float red[128 * 64];  // 32 KB, tail-only transpose scratch

    const int lane = threadIdx.x;              // 0..63
    const int ty   = threadIdx.y;              // 0..3
    const int bid  = blockIdx.x;
    const int bx   = bid / SIB;                // 0..3  (rq-group of 8 rows)
    const int rem  = bid % SIB;
    const int oc   = rem >> 2;                 // 0..171
    const int ks   = rem & 3;                  // 0..3  (K-split)
    const int rq0  = bx * 8 + ty * 2;          // packed rows rq0, rq0+1

    const int kbase = ks * KC;
    const int gb = oc * IN_ + kbase;

    // ---- prefetch ALL Wq for this wave: 8 independent dwordx4 (32 VGPR) ----
    const int* __restrict__ wqA = Wq + (long)rq0 * G_ + gb;
    const int* __restrict__ wqB = wqA + G_;
    int4 qA[ITERS], qB[ITERS];
#pragma unroll
    for (int it = 0; it < ITERS; ++it) {
        qA[it] = *(const int4*)(wqA + it * 256 + lane * 4);
        qB[it] = *(const int4*)(wqB + it * 256 + lane * 4);
    }

    // acc[0]=hi(rq0) acc[1]=lo(rq0) acc[2]=hi(rq0+1) acc[3]=lo(rq0+1)
    float acc[4][8];
#pragma unroll
    for (int r = 0; r < 4; ++r)
#pragma unroll
        for (int b = 0; b < 8; ++b) acc[r][b] = 0.f;

#pragma unroll
    for (int it = 0; it < ITERS; ++it) {
        const int i = it * 256 + lane * 4;
        const float4 s4 = *(const float4*)(scale + gb + i);
        const float4 z4 = *(const float4*)(zero + gb + i);
        const float ss[4] = {s4.x, s4.y, s4.z, s4.w};
        const float zs[4] = {-z4.x * s4.x, -z4.y * s4.y, -z4.z * s4.z, -z4.w * s4.w};
        const int qsA[4] = {qA[it].x, qA[it].y, qA[it].z, qA[it].w};
        const int qsB[4] = {qB[it].x, qB[it].y, qB[it].z, qB[it].w};

        float w[4][4];  // [hiA, loA, hiB, loB][j]
#pragma unroll
        for (int j = 0; j < 4; ++j) {
            w[0][j] = fmaf((float)((qsA[j] >> 4) & 0xF), ss[j], zs[j]);
            w[1][j] = fmaf((float)( qsA[j]       & 0xF), ss[j], zs[j]);
            w[2][j] = fmaf((float)((qsB[j] >> 4) & 0xF), ss[j], zs[j]);
            w[3][j] = fmaf((float)( qsB[j]       & 0xF), ss[j], zs[j]);
        }
#pragma unroll
        for (int b = 0; b < 8; ++b) {
            const float4 xb = *(const float4*)(x + b * IN_ + kbase + i);
#pragma unroll
            for (int r = 0; r < 4; ++r) {
                float a = acc[r][b];
                a = fmaf(xb.x, w[r][0], a);
                a = fmaf(xb.y, w[r][1], a);
                a = fmaf(xb.z, w[r][2], a);
                a = fmaf(xb.w, w[r][3], a);
                acc[r][b] = a;
            }
        }
    }

    // ---- XOR-swizzled LDS transpose reduce over the 64 K-slice lanes ----
    // slot for (o, lane) = o*64 + (lane ^ ((o&7)<<3)); writes are a lane
    // permutation (2 lanes/bank = free), b128 reads land ~4-way.
    const int obase = ty * 32;
#pragma unroll
    for (int r = 0; r < 4; ++r)
#pragma unroll
        for (int b = 0; b < 8; ++b) {
            const int o = obase + r * 8 + b;
            red[o * 64 + (lane ^ ((o & 7) << 3))] = acc[r][b];
        }
    __syncthreads();

    const int t = ty * 64 + lane;  // 0..255
    if (t < 128) {
        const int o = t;           // local output index
        const int c = (o & 7) << 3;
        float s = 0.f;
#pragma unroll
        for (int j = 0; j < 16; ++j) {
            const float4 v = *(const float4*)(red + o * 64 + ((j * 4) ^ c));
            s += (v.x + v.y) + (v.z + v.w);
        }
        // decode o -> (wave, r, b) matching the acc ordering above
        const int w_  = o >> 5;
        const int r   = (o >> 3) & 3;
        const int b   = o & 7;
        const int rq  = bx * 8 + w_ * 2 + (r >> 1);
        const int row = rq + ((r & 1) ? 32 : 0);
        ws[((long)ks * 8 + b) * OUT_ + row * OC_ + oc] = s;
    }
}

__global__ void hqq_reduce(const float* __restrict__ ws,
                           const float* __restrict__ bias,
                           float* __restrict__ out) {
    const int t = blockIdx.x * 256 + threadIdx.x;
    if (t >= 8 * OUT_) return;
    const int o = t % OUT_;
    float v = bias[o];
#pragma unroll
    for (int k = 0; k < KS; ++k) v += ws[k * 8 * OUT_ + t];
    out[t] = v;
}

extern "C" void kernel_launch(void* const* d_in, const int* in_sizes, int n_in,
                              void* d_out, int out_size, void* d_ws, size_t ws_size,
                              hipStream_t stream) {
    const int*   Wq    = (const int*)d_in[0];    // [32, 704512] int32
    const float* scale = (const float*)d_in[1];  // [1, 704512]
    const float* zero  = (const float*)d_in[2];  // [1, 704512]
    const float* x     = (const float*)d_in[3];  // [8, 1, 4096]
    const float* bias  = (const float*)d_in[4];  // [11008]
    float* out = (float*)d_out;                  // [8, 1, 11008]
    float* ws  = (float*)d_ws;                   // KS*8*11008 floats = 1.38 MB

    dim3 grid(NB);          // 2752, XCD-aligned sibling groups
    dim3 block(64, 4);
    hqq_gemv<<<grid, block, 0, stream>>>(Wq, scale, zero, x, ws);
    hqq_reduce<<<(8 * OUT_ + 255) / 256, 256, 0, stream>>>(ws, bias, out);
}

// Round 2
// 144.341 us; speedup vs baseline: 1.0544x; 1.0544x over previous
//
#include <hip/hip_runtime.h>

// HQQ 4-bit dequant + linear (Llama-7B up-proj, decode: 8 tokens)
// OUT=11008, IN=4096, GS=64, G=704512, OC=172 (=G/IN; OUT=64*OC)
// W_q: [32, G] int32 (one byte per word: hi nibble -> unpacked row rq,
//      lo nibble -> row rq+32 of the [64, G] tensor)
// Mapping: W_r[o, i] with r=o/172, oc=o%172, g=oc*4096+i.
//
// R5 theory: R4's (256,4) bound + hoisted global x loads (~140 live VGPR)
// forced spills/clamped scheduling -> occupancy gain never materialized
// (neutral 152 us). This version removes loop-side VGPR pressure:
//  - s/z/x staged via global_load_lds width=16 (async DMA, no VGPR
//    round-trip, no per-lane address regs in the loop). 40 KB LDS.
//  - Loop reads are ds_read_b128 from LDS; only Wq prefetch (32 VGPR)
//    stays in registers. Census ~105 VGPR -> true 4 blocks/CU.
//  - Coalesced 128-float block store to ws (reduce kernel decodes).
//  - Tail transpose swizzle (o&7)<<2 spreads b128 reads over all 8 slots.

#define OUT_ 11008
#define IN_ 4096
#define G_ 704512
#define OC_ 172
#define KS 4
#define KC (IN_ / KS)      // 1024
#define ITERS (KC / 256)   // 4
#define SIB (OC_ * KS)     // 688; 688%8==0 so bx-siblings land on same XCD
#define NB (4 * SIB)       // 2752 blocks

typedef const __attribute__((address_space(1))) void* gptr1_t;
typedef __attribute__((address_space(3))) void* sptr3_t;

__device__ __forceinline__ void gload_lds16(const float* g, float* l) {
    // dest is wave-uniform; HW adds lane*16B. src is per-lane.
    __builtin_amdgcn_global_load_lds((gptr1_t)g, (sptr3_t)l, 16, 0, 0);
}

__global__ __launch_bounds__(256, 4)
void hqq_gemv(const int* __restrict__ Wq, const float* __restrict__ scale,
              const float* __restrict__ zero, const float* __restrict__ x,
              float* __restrict__ ws) {
    __shared__ float x_lds[8 * KC];   // 32 KB; reused as red[128*64] at tail
    __shared__ float s_lds[KC];       // 4 KB
    __shared__ float z_lds[KC];       // 4 KB

    const int lane = threadIdx.x;              // 0..63
    const int ty   = threadIdx.y;              // 0..3
    const int tid  = ty * 64 + lane;
    const int bid  = blockIdx.x;
    const int bx   = bid / SIB;                // 0..3  (rq-group of 8 rows)
    const int rem  = bid % SIB;
    const int oc   = rem >> 2;                 // 0..171
    const int ks   = rem & 3;                  // 0..3
    const int rq0  = bx * 8 + ty * 2;          // packed rows rq0, rq0+1

    const int kbase = ks * KC;
    const int gb = oc * IN_ + kbase;

    // ---- async-stage s, z, x into LDS (wave-uniform dest, per-lane src) ----
    const int wf = ty * 256;                   // wave's float offset per round
    gload_lds16(scale + gb + wf + lane * 4, s_lds + wf);
    gload_lds16(zero  + gb + wf + lane * 4, z_lds + wf);
#pragma unroll
    for (int r = 0; r < 8; ++r) {              // round r covers batch b=r
        gload_lds16(x + r * IN_ + kbase + wf + lane * 4, x_lds + r * 1024 + wf);
    }

    // ---- prefetch ALL Wq for this wave: 8 independent dwordx4 (32 VGPR) ----
    const int* __restrict__ wqA = Wq + (long)rq0 * G_ + gb;
    const int* __restrict__ wqB = wqA + G_;
    int4 qA[ITERS], qB[ITERS];
#pragma unroll
    for (int it = 0; it < ITERS; ++it) {
        qA[it] = *(const int4*)(wqA + it * 256 + lane * 4);
        qB[it] = *(const int4*)(wqB + it * 256 + lane * 4);
    }

    __syncthreads();  // drains vmcnt: LDS-DMA + Wq regs all resident

    // acc[0]=hi(rq0) acc[1]=lo(rq0) acc[2]=hi(rq0+1) acc[3]=lo(rq0+1)
    float acc[4][8];
#pragma unroll
    for (int r = 0; r < 4; ++r)
#pragma unroll
        for (int b = 0; b < 8; ++b) acc[r][b] = 0.f;

#pragma unroll
    for (int it = 0; it < ITERS; ++it) {
        const int i = it * 256 + lane * 4;
        const float4 s4 = *(const float4*)(s_lds + i);
        const float4 z4 = *(const float4*)(z_lds + i);
        const float ss[4] = {s4.x, s4.y, s4.z, s4.w};
        const float zs[4] = {-z4.x * s4.x, -z4.y * s4.y, -z4.z * s4.z, -z4.w * s4.w};
        const int qsA[4] = {qA[it].x, qA[it].y, qA[it].z, qA[it].w};
        const int qsB[4] = {qB[it].x, qB[it].y, qB[it].z, qB[it].w};

        float w[4][4];  // [hiA, loA, hiB, loB][j]
#pragma unroll
        for (int j = 0; j < 4; ++j) {
            w[0][j] = fmaf((float)((qsA[j] >> 4) & 0xF), ss[j], zs[j]);
            w[1][j] = fmaf((float)( qsA[j]       & 0xF), ss[j], zs[j]);
            w[2][j] = fmaf((float)((qsB[j] >> 4) & 0xF), ss[j], zs[j]);
            w[3][j] = fmaf((float)( qsB[j]       & 0xF), ss[j], zs[j]);
        }
#pragma unroll
        for (int b = 0; b < 8; ++b) {
            const float4 xb = *(const float4*)(x_lds + b * KC + i);
#pragma unroll
            for (int r = 0; r < 4; ++r) {
                float a = acc[r][b];
                a = fmaf(xb.x, w[r][0], a);
                a = fmaf(xb.y, w[r][1], a);
                a = fmaf(xb.z, w[r][2], a);
                a = fmaf(xb.w, w[r][3], a);
                acc[r][b] = a;
            }
        }
    }

    // ---- LDS transpose reduce over the 64 K-slice lanes ----
    // red row o holds acc values from all 64 lanes; write side is a lane
    // permutation (free); read side: slot = (j ^ (o&7)) % 8 -> all 8 slots.
    float* red = x_lds;                        // x no longer needed
    __syncthreads();
    const int obase = ty * 32;
#pragma unroll
    for (int r = 0; r < 4; ++r)
#pragma unroll
        for (int b = 0; b < 8; ++b) {
            const int o = obase + r * 8 + b;
            red[o * 64 + (lane ^ ((o & 7) << 2))] = acc[r][b];
        }
    __syncthreads();

    if (tid < 128) {
        const int o = tid;                     // o = w_*32 + r*8 + b
        const int c = (o & 7) << 2;
        float s = 0.f;
#pragma unroll
        for (int j = 0; j < 16; ++j) {
            const float4 v = *(const float4*)(red + o * 64 + ((j * 4) ^ c));
            s += (v.x + v.y) + (v.z + v.w);
        }
        // coalesced: this block's 128 partials are contiguous
        ws[(long)((bx * OC_ + oc) * KS + ks) * 128 + o] = s;
    }
}

__global__ void hqq_reduce(const float* __restrict__ ws,
                           const float* __restrict__ bias,
                           float* __restrict__ out) {
    const int t = blockIdx.x * 256 + threadIdx.x;
    if (t >= 8 * OUT_) return;
    const int o = t % OUT_;
    const int b = t / OUT_;
    const int row = o / OC_;                   // 0..63
    const int oc  = o % OC_;
    const int rq  = row & 31;                  // packed row
    const int hi  = row >> 5;                  // 0 = hi nibble rows, 1 = lo
    const int bx  = rq >> 3;
    const int w_  = (rq >> 1) & 3;
    const int r   = ((rq & 1) << 1) | hi;
    const int base = ((bx * OC_ + oc) * KS) * 128 + w_ * 32 + r * 8 + b;
    float v = bias[o];
#pragma unroll
    for (int k = 0; k < KS; ++k) v += ws[base + k * 128];
    out[t] = v;
}

extern "C" void kernel_launch(void* const* d_in, const int* in_sizes, int n_in,
                              void* d_out, int out_size, void* d_ws, size_t ws_size,
                              hipStream_t stream) {
    const int*   Wq    = (const int*)d_in[0];    // [32, 704512] int32
    const float* scale = (const float*)d_in[1];  // [1, 704512]
    const float* zero  = (const float*)d_in[2];  // [1, 704512]
    const float* x     = (const float*)d_in[3];  // [8, 1, 4096]
    const float* bias  = (const float*)d_in[4];  // [11008]
    float* out = (float*)d_out;                  // [8, 1, 11008]
    float* ws  = (float*)d_ws;                   // NB*128 floats = 1.38 MB

    dim3 grid(NB);          // 2752, XCD-aligned sibling groups
    dim3 block(64, 4);
    hqq_gemv<<<grid, block, 0, stream>>>(Wq, scale, zero, x, ws);
    hqq_reduce<<<(8 * OUT_ + 255) / 256, 256, 0, stream>>>(ws, bias, out);
}